// Round 3
// baseline (118.453 us; speedup 1.0000x reference)
//
#include <hip/hip_runtime.h>
#include <math.h>

#define BB 8
#define TT 1024
#define CC 64

typedef float f32x4 __attribute__((ext_vector_type(4)));
typedef short short8 __attribute__((ext_vector_type(8)));
typedef unsigned int u32x4 __attribute__((ext_vector_type(4)));
typedef unsigned short u16;

static __device__ __forceinline__ u16 f2bf(float f) {
    union { float f; unsigned int u; } v; v.f = f;
    unsigned int r = v.u + 0x7fffu + ((v.u >> 16) & 1u);
    return (u16)(r >> 16);
}
static __device__ __forceinline__ float bf2f(u16 h) {
    union { unsigned int u; float f; } v; v.u = ((unsigned int)h) << 16; return v.f;
}
static __device__ __forceinline__ short8 pack8(const float* p) {
    float4 a = *(const float4*)p;
    float4 b = *(const float4*)(p + 4);
    short8 r;
    r[0] = (short)f2bf(a.x); r[1] = (short)f2bf(a.y); r[2] = (short)f2bf(a.z); r[3] = (short)f2bf(a.w);
    r[4] = (short)f2bf(b.x); r[5] = (short)f2bf(b.y); r[6] = (short)f2bf(b.z); r[7] = (short)f2bf(b.w);
    return r;
}

#define MFMA16(a, b, c) __builtin_amdgcn_mfma_f32_16x16x32_bf16((a), (b), (c), 0, 0, 0)

// Workspace layout (bytes). Ypart/Lpart GONE (R3: attention finishes in one
// kernel; no cross-block partials, no fences — R1 lesson: fences cost ~100x
// a kernel boundary on gfx950).
#define OFF_QBF      ((size_t)0)             // q pre-scaled by 0.125
#define OFF_KBF      ((size_t)1048576)
#define OFF_VT       ((size_t)2097152)       // [b][c][t]
#define OFF_EKP      ((size_t)3145728)       // 1088*64 bf16 (rows d=-32..1055)
#define OFF_EVT      ((size_t)3284992)       // 64*1088 bf16 (cols d=-32..1055)
#define OFF_WPROJ    ((size_t)3424256)       // 64*64 bf16
#define WS_NEED      ((size_t)3432448)

// ---------------------------------------------------------------------------
// K1: qkv + prep. Grid (576, 3): x<512 -> qkv row-tile, y = oc group; one oc
// chunk per wave. x>=512 & y==0 -> pad fills. (Verified R6/R7 structure.)
// ---------------------------------------------------------------------------
__global__ __launch_bounds__(256) void qkv_prep_kernel(const float* __restrict__ x,
                                                       const float* __restrict__ Wqkv,
                                                       const float* __restrict__ bqkv,
                                                       const float* __restrict__ embk,
                                                       const float* __restrict__ embv,
                                                       const float* __restrict__ Wproj,
                                                       u16* __restrict__ q_bf,
                                                       u16* __restrict__ k_bf,
                                                       u16* __restrict__ vT_bf,
                                                       u16* __restrict__ embk_pad,
                                                       u16* __restrict__ embvT_pad,
                                                       u16* __restrict__ Wproj_bf) {
    const int blk = blockIdx.x;
    const int grp = blockIdx.y;
    const int tid = threadIdx.x;

    if (blk >= 512) {
        if (grp != 0) return;
        const int idx0 = (blk - 512) * 256 + tid;
        const int stride = 64 * 256;
        for (int i = idx0; i < 1088 * CC; i += stride) {
            int r = i >> 6, c = i & 63, d = r - 32;
            embk_pad[i] = (d >= 0 && d < TT) ? f2bf(embk[d * CC + c]) : (u16)0;
        }
        for (int i = idx0; i < CC * 1088; i += stride) {
            int c = i / 1088, col = i - c * 1088, d = col - 32;
            embvT_pad[i] = (d >= 0 && d < TT) ? f2bf(embv[d * CC + c]) : (u16)0;
        }
        for (int i = idx0; i < CC * CC; i += stride) Wproj_bf[i] = f2bf(Wproj[i]);
        return;
    }

    const int w = tid >> 6, lane = tid & 63, quad = lane >> 4, l15 = lane & 15;
    const int row0 = blk * 16;
    const int oc = grp * 4 + w;                 // 0..11
    __shared__ float vt[4][16][17];

    const float* xr = x + (size_t)(row0 + l15) * CC + quad * 8;
    short8 a0 = pack8(xr);
    short8 a1 = pack8(xr + 32);

    const float* wr = Wqkv + (size_t)(oc * 16 + l15) * CC + quad * 8;
    short8 b0 = pack8(wr);
    short8 b1 = pack8(wr + 32);
    f32x4 acc = {0.f, 0.f, 0.f, 0.f};
    acc = MFMA16(a0, b0, acc);
    acc = MFMA16(a1, b1, acc);
    const float bias = bqkv[oc * 16 + l15];

    if (oc < 4) {
        const int c = oc * 16 + l15;
        #pragma unroll
        for (int r = 0; r < 4; ++r)
            q_bf[(size_t)(row0 + quad * 4 + r) * CC + c] = f2bf((acc[r] + bias) * 0.125f);
    } else if (oc < 8) {
        const int c = (oc - 4) * 16 + l15;
        #pragma unroll
        for (int r = 0; r < 4; ++r)
            k_bf[(size_t)(row0 + quad * 4 + r) * CC + c] = f2bf(acc[r] + bias);
    } else {
        #pragma unroll
        for (int r = 0; r < 4; ++r) vt[w][quad * 4 + r][l15] = acc[r] + bias;
        const int c_l = lane >> 2;
        const int tbase = (lane & 3) * 4;
        const int b = row0 >> 10, t0v = row0 & (TT - 1);
        u16 p[4];
        #pragma unroll
        for (int tt2 = 0; tt2 < 4; ++tt2) p[tt2] = f2bf(vt[w][tbase + tt2][c_l]);
        unsigned long long pk = (unsigned long long)p[0] | ((unsigned long long)p[1] << 16)
                              | ((unsigned long long)p[2] << 32) | ((unsigned long long)p[3] << 48);
        *(unsigned long long*)&vT_bf[(size_t)(b * CC + (oc - 8) * 16 + c_l) * TT + t0v + tbase] = pk;
    }
}

// ---------------------------------------------------------------------------
// K2 (R3): ONE kernel finishes attention. Grid (64, 8), 512 thr (8 waves).
// Wave w loops s-tiles st = w, w+8, ... (<= 4 iterations at tt=63),
// accumulating (Y, L) in registers — softmax is linear (fixed-max), so
// accumulation order is free. Per-tile math identical to the verified R0
// body. Block-local 8-way merge + normalize + Wproj MFMA epilogue. No
// Ypart/Lpart global traffic, no K3 launch, no fences. tt is reversed so
// heavy tiles dispatch first. Cross-iteration ILP: no barrier inside the
// loop, so iteration i+1's global loads overlap iteration i's MFMAs.
// ---------------------------------------------------------------------------
#define WBSTRIDE 4160   // per-wave LDS: pt(1280) + a2(2304) = 3584; merge 4096

__global__ __launch_bounds__(512) void attn_loop_kernel(const u16* __restrict__ q_bf,
                                                        const u16* __restrict__ k_bf,
                                                        const u16* __restrict__ vT_bf,
                                                        const u16* __restrict__ embk_pad,
                                                        const u16* __restrict__ embvT_pad,
                                                        const u16* __restrict__ Wproj_bf,
                                                        const float* __restrict__ bproj,
                                                        float* __restrict__ out) {
    const int b = blockIdx.y;
    const int tt = 63 - blockIdx.x;               // heavy tiles first
    const int t0 = tt * 16;
    const int nst = (t0 >> 5) + 1;

    const int tid = threadIdx.x;
    const int w = tid >> 6, lane = tid & 63, quad = lane >> 4, l15 = lane & 15;

    __shared__ __align__(16) char wbuf[8][WBSTRIDE];
    __shared__ float lpart[8][16];
    __shared__ float Ls[16];
    __shared__ __align__(16) u16 yA[16 * 64];

    u16* pt = (u16*)(wbuf[w]);                    // 16*40 bf16
    u16* a2 = (u16*)(wbuf[w] + 1280);             // 16*72 bf16 (skewed P)

    f32x4 acc[4];
    #pragma unroll
    for (int nb = 0; nb < 4; ++nb) acc[nb] = (f32x4){0.f, 0.f, 0.f, 0.f};
    float rsum[4] = {0.f, 0.f, 0.f, 0.f};

    // hoisted Q fragments (q pre-scaled by 0.125) — reused across all s-tiles
    const u16* qrow = q_bf + (size_t)((b << 10) + t0 + l15) * CC;
    short8 aq0 = *(const short8*)(qrow + quad * 8);
    short8 aq1 = *(const short8*)(qrow + 32 + quad * 8);

    for (int st = w; st < nst; st += 8) {
        const int s0 = st * 32;

        // ---- content scores: 16x32 tile ----
        f32x4 sc[2];
        #pragma unroll
        for (int cb = 0; cb < 2; ++cb) {
            const u16* krow = k_bf + (size_t)((b << 10) + s0 + cb * 16 + l15) * CC;
            short8 kb0 = *(const short8*)(krow + quad * 8);
            short8 kb1 = *(const short8*)(krow + 32 + quad * 8);
            f32x4 a = {0.f, 0.f, 0.f, 0.f};
            a = MFMA16(aq0, kb0, a);
            a = MFMA16(aq1, kb1, a);
            sc[cb] = a;
        }

        // ---- relative band: 3 MFMAs kept in C-layout registers ----
        const int dbase = t0 - s0 - 31;
        f32x4 bnd[3];
        #pragma unroll
        for (int nb = 0; nb < 3; ++nb) {
            const u16* erow = embk_pad + (size_t)(dbase + 32 + nb * 16 + l15) * CC;
            short8 eb0 = *(const short8*)(erow + quad * 8);
            short8 eb1 = *(const short8*)(erow + 32 + quad * 8);
            f32x4 a = {0.f, 0.f, 0.f, 0.f};
            a = MFMA16(aq0, eb0, a);
            a = MFMA16(aq1, eb1, a);
            bnd[nb] = a;
        }

        // ---- band via cross-lane shuffles + masked p = exp(score) ----
        u16 pb0[4], pb1[4];
        #pragma unroll
        for (int r = 0; r < 4; ++r) {
            const int i = quad * 4 + r;
            const int u0 = 31 + i - l15;
            const int src = (quad << 4) | (u0 & 15);
            const float v0 = __shfl(bnd[0][r], src, 64);
            const float v1 = __shfl(bnd[1][r], src, 64);
            const float v2 = __shfl(bnd[2][r], src, 64);
            const bool hi = (u0 >= 32);
            {   // cb = 0: j = l15
                const float rb = hi ? v2 : v1;
                const int d = t0 - s0 + i - l15;
                float pv = (d >= 0) ? __expf(sc[0][r] + rb) : 0.f;
                pb0[r] = f2bf(pv);
                rsum[r] += bf2f(pb0[r]);
            }
            {   // cb = 1: j = 16+l15
                const float rb = hi ? v1 : v0;
                const int d = t0 - s0 + i - 16 - l15;
                float pv = (d >= 0) ? __expf(sc[1][r] + rb) : 0.f;
                pb1[r] = f2bf(pv);
                rsum[r] += bf2f(pb1[r]);
            }
        }

        // ---- write P: row-major (pt) and skewed (a2); in-wave DS order ----
        u32x4 z = {0u, 0u, 0u, 0u};
        #pragma unroll
        for (int e = 0; e < 3; ++e) {              // 144 u32x4 = 16*72 u16
            int idx = lane + e * 64;
            if (idx < 144) ((u32x4*)a2)[idx] = z;
        }
        #pragma unroll
        for (int r = 0; r < 4; ++r) {
            const int i = quad * 4 + r;
            pt[i * 40 + l15] = pb0[r];
            pt[i * 40 + 16 + l15] = pb1[r];
            a2[i * 72 + (32 + i - l15)] = pb0[r];
            a2[i * 72 + (16 + i - l15)] = pb1[r];
        }

        // ---- y1 += P @ V ----
        short8 aP = *(const short8*)(pt + l15 * 40 + quad * 8);
        #pragma unroll
        for (int nb = 0; nb < 4; ++nb) {
            const u16* vrow = vT_bf + ((size_t)(b * CC + nb * 16 + l15) << 10) + s0;
            short8 bv = *(const short8*)(vrow + quad * 8);
            acc[nb] = MFMA16(aP, bv, acc[nb]);
        }

        // ---- y2 += skew(P) @ embv band ----
        const int dcol0 = t0 - s0;
        #pragma unroll
        for (int kk = 0; kk < 2; ++kk) {
            short8 a2f = *(const short8*)(a2 + l15 * 72 + kk * 32 + quad * 8);
            #pragma unroll
            for (int nb = 0; nb < 4; ++nb) {
                const u16* erow = embvT_pad + (size_t)(nb * 16 + l15) * 1088 + dcol0 + kk * 32 + quad * 8;
                short8 be = *(const short8*)erow;
                acc[nb] = MFMA16(a2f, be, acc[nb]);
            }
        }
    }

    // ---- per-wave row-sum reduction ----
    #pragma unroll
    for (int msk = 1; msk < 16; msk <<= 1)
        #pragma unroll
        for (int r = 0; r < 4; ++r) rsum[r] += __shfl_xor(rsum[r], msk, 64);
    if (l15 == 0) {
        #pragma unroll
        for (int r = 0; r < 4; ++r) lpart[w][quad * 4 + r] = rsum[r];
    }

    // ---- wave partial Y -> unioned per-wave LDS region ----
    float* ypw = (float*)(wbuf[w]);
    #pragma unroll
    for (int nb = 0; nb < 4; ++nb)
        #pragma unroll
        for (int r = 0; r < 4; ++r)
            ypw[(quad * 4 + r) * 64 + nb * 16 + l15] = acc[nb][r];
    __syncthreads();

    // ---- merge 8 wave partials (threads 0..255 own the 16x64 tile) ----
    const int i = tid >> 4, c0 = (tid * 4) & 63;
    float4 Y = {0.f, 0.f, 0.f, 0.f};
    if (tid < 256) {
        #pragma unroll
        for (int ww = 0; ww < 8; ++ww) {
            const float* src = (const float*)(wbuf[ww]);
            Y.x += src[i * 64 + c0];
            Y.y += src[i * 64 + c0 + 1];
            Y.z += src[i * 64 + c0 + 2];
            Y.w += src[i * 64 + c0 + 3];
        }
        if (tid < 16) {
            float L = 0.f;
            #pragma unroll
            for (int ww = 0; ww < 8; ++ww) L += lpart[ww][tid];
            Ls[tid] = L;
        }
    }
    __syncthreads();

    // ---- normalize + bf16 pack ----
    if (tid < 256) {
        const float inv = 1.0f / Ls[i];
        u16 y4[4] = { f2bf(Y.x * inv), f2bf(Y.y * inv), f2bf(Y.z * inv), f2bf(Y.w * inv) };
        *(unsigned long long*)&yA[i * 64 + c0] =
            (unsigned long long)y4[0] | ((unsigned long long)y4[1] << 16)
          | ((unsigned long long)y4[2] << 32) | ((unsigned long long)y4[3] << 48);
    }
    __syncthreads();

    // ---- proj epilogue: waves 0..3 -> output cols w*16 .. +15 ----
    if (w < 4) {
        short8 a0 = *(const short8*)(yA + l15 * 64 + quad * 8);
        short8 a1 = *(const short8*)(yA + l15 * 64 + 32 + quad * 8);
        const u16* wrow = Wproj_bf + (size_t)(w * 16 + l15) * CC;
        short8 wb0 = *(const short8*)(wrow + quad * 8);
        short8 wb1 = *(const short8*)(wrow + 32 + quad * 8);
        f32x4 o = {0.f, 0.f, 0.f, 0.f};
        o = MFMA16(a0, wb0, o);
        o = MFMA16(a1, wb1, o);
        const float bias = bproj[w * 16 + l15];
        #pragma unroll
        for (int r = 0; r < 4; ++r)
            out[(size_t)((b << 10) + t0 + quad * 4 + r) * CC + w * 16 + l15] = o[r] + bias;
    }
}

// ===========================================================================
// Fallback path (round-1 verified fp32 kernels) — used if ws_size < needed.
// ===========================================================================
__global__ __launch_bounds__(192) void qkv_kernel(const float* __restrict__ x,
                                                  const float* __restrict__ Wqkv,
                                                  const float* __restrict__ bqkv,
                                                  float* __restrict__ qkv) {
    __shared__ __align__(16) float xs[CC];
    const int row = blockIdx.x;
    const int j = threadIdx.x;
    if (j < CC) xs[j] = x[row * CC + j];
    __syncthreads();
    const float* w = Wqkv + j * CC;
    float acc = bqkv[j];
    #pragma unroll
    for (int c = 0; c < CC; c += 4) {
        float4 wq = *(const float4*)(w + c);
        float4 xq = *(const float4*)(xs + c);
        acc += wq.x * xq.x + wq.y * xq.y + wq.z * xq.z + wq.w * xq.w;
    }
    qkv[row * 192 + j] = acc;
}

__global__ __launch_bounds__(256) void attn_kernel(const float* __restrict__ qkv,
                                                   const float* __restrict__ embk,
                                                   const float* __restrict__ embv,
                                                   const float* __restrict__ Wproj,
                                                   const float* __restrict__ bproj,
                                                   float* __restrict__ out) {
    __shared__ __align__(16) float qs[CC];
    __shared__ __align__(16) float sc[TT];
    __shared__ float red[256];
    __shared__ float yred[4][CC];
    const int bt = blockIdx.x;
    const int b = bt >> 10, t = bt & (TT - 1);
    const int tid = threadIdx.x;
    if (tid < CC) qs[tid] = qkv[bt * 192 + tid];
    __syncthreads();
    float lmax = -1e30f;
    for (int s = tid; s <= t; s += 256) {
        const float* krow = qkv + (b * TT + s) * 192 + 64;
        const float* erow = embk + (t - s) * CC;
        float acc = 0.f;
        #pragma unroll
        for (int c = 0; c < CC; c += 4) {
            float4 kq = *(const float4*)(krow + c);
            float4 eq = *(const float4*)(erow + c);
            float4 qq = *(const float4*)(qs + c);
            acc += qq.x * (kq.x + eq.x) + qq.y * (kq.y + eq.y)
                 + qq.z * (kq.z + eq.z) + qq.w * (kq.w + eq.w);
        }
        acc *= 0.125f;
        sc[s] = acc;
        lmax = fmaxf(lmax, acc);
    }
    red[tid] = lmax; __syncthreads();
    for (int off = 128; off > 0; off >>= 1) { if (tid < off) red[tid] = fmaxf(red[tid], red[tid + off]); __syncthreads(); }
    const float m = red[0]; __syncthreads();
    float lsum = 0.f;
    for (int s = tid; s <= t; s += 256) { float e = __expf(sc[s] - m); sc[s] = e; lsum += e; }
    red[tid] = lsum; __syncthreads();
    for (int off = 128; off > 0; off >>= 1) { if (tid < off) red[tid] += red[tid + off]; __syncthreads(); }
    const float inv = 1.0f / red[0]; __syncthreads();
    const int c = tid & 63, g = tid >> 6;
    float acc = 0.f;
    for (int s = g; s <= t; s += 4) {
        float p = sc[s];
        float vv = qkv[(b * TT + s) * 192 + 128 + c];
        float ev = embv[(t - s) * CC + c];
        acc += p * (vv + ev);
    }
    yred[g][c] = acc * inv;
    __syncthreads();
    if (tid < CC) qs[tid] = yred[0][tid] + yred[1][tid] + yred[2][tid] + yred[3][tid];
    __syncthreads();
    if (tid < CC) {
        const float* w = Wproj + tid * CC;
        float o = bproj[tid];
        #pragma unroll
        for (int cc2 = 0; cc2 < CC; cc2 += 4) {
            float4 wq = *(const float4*)(w + cc2);
            float4 yq = *(const float4*)(qs + cc2);
            o += wq.x * yq.x + wq.y * yq.y + wq.z * yq.z + wq.w * yq.w;
        }
        out[bt * CC + tid] = o;
    }
}

extern "C" void kernel_launch(void* const* d_in, const int* in_sizes, int n_in,
                              void* d_out, int out_size, void* d_ws, size_t ws_size,
                              hipStream_t stream) {
    const float* x     = (const float*)d_in[0];
    const float* Wqkv  = (const float*)d_in[1];
    const float* bqkv  = (const float*)d_in[2];
    const float* embk  = (const float*)d_in[3];
    const float* embv  = (const float*)d_in[4];
    const float* Wproj = (const float*)d_in[5];
    const float* bproj = (const float*)d_in[6];
    float* out = (float*)d_out;

    if (ws_size < WS_NEED) {
        float* qkv = (float*)d_ws;
        qkv_kernel<<<BB * TT, 192, 0, stream>>>(x, Wqkv, bqkv, qkv);
        attn_kernel<<<BB * TT, 256, 0, stream>>>(qkv, embk, embv, Wproj, bproj, out);
        return;
    }

    char* ws = (char*)d_ws;
    u16* q_bf       = (u16*)(ws + OFF_QBF);
    u16* k_bf       = (u16*)(ws + OFF_KBF);
    u16* vT_bf      = (u16*)(ws + OFF_VT);
    u16* embk_pad   = (u16*)(ws + OFF_EKP);
    u16* embvT_pad  = (u16*)(ws + OFF_EVT);
    u16* Wproj_bf   = (u16*)(ws + OFF_WPROJ);

    qkv_prep_kernel<<<dim3(576, 3), 256, 0, stream>>>(x, Wqkv, bqkv, embk, embv, Wproj,
                                                      q_bf, k_bf, vT_bf, embk_pad, embvT_pad, Wproj_bf);
    attn_loop_kernel<<<dim3(64, 8), 512, 0, stream>>>(q_bf, k_bf, vT_bf, embk_pad, embvT_pad,
                                                      Wproj_bf, bproj, out);
}

// Round 4
// 117.475 us; speedup vs baseline: 1.0083x; 1.0083x over previous
//
#include <hip/hip_runtime.h>
#include <math.h>

#define BB 8
#define TT 1024
#define CC 64

typedef float f32x4 __attribute__((ext_vector_type(4)));
typedef short short8 __attribute__((ext_vector_type(8)));
typedef unsigned int u32x4 __attribute__((ext_vector_type(4)));
typedef unsigned short u16;

static __device__ __forceinline__ u16 f2bf(float f) {
    union { float f; unsigned int u; } v; v.f = f;
    unsigned int r = v.u + 0x7fffu + ((v.u >> 16) & 1u);
    return (u16)(r >> 16);
}
static __device__ __forceinline__ float bf2f(u16 h) {
    union { unsigned int u; float f; } v; v.u = ((unsigned int)h) << 16; return v.f;
}
static __device__ __forceinline__ short8 pack8(const float* p) {
    float4 a = *(const float4*)p;
    float4 b = *(const float4*)(p + 4);
    short8 r;
    r[0] = (short)f2bf(a.x); r[1] = (short)f2bf(a.y); r[2] = (short)f2bf(a.z); r[3] = (short)f2bf(a.w);
    r[4] = (short)f2bf(b.x); r[5] = (short)f2bf(b.y); r[6] = (short)f2bf(b.z); r[7] = (short)f2bf(b.w);
    return r;
}

#define MFMA16(a, b, c) __builtin_amdgcn_mfma_f32_16x16x32_bf16((a), (b), (c), 0, 0, 0)

// Workspace layout (bytes). Ypart/Lpart gone (single attention kernel; no
// cross-block partials, no fences — R1 lesson: fences cost ~100x a kernel
// boundary on gfx950).
#define OFF_QBF      ((size_t)0)             // q pre-scaled by 0.125
#define OFF_KBF      ((size_t)1048576)
#define OFF_VT       ((size_t)2097152)       // [b][c][t]
#define OFF_EKP      ((size_t)3145728)       // 1088*64 bf16 (rows d=-32..1055)
#define OFF_EVT      ((size_t)3284992)       // 64*1088 bf16 (cols d=-32..1055)
#define OFF_WPROJ    ((size_t)3424256)       // 64*64 bf16
#define WS_NEED      ((size_t)3432448)

// ---------------------------------------------------------------------------
// K1: qkv + prep. Grid (576, 3): x<512 -> qkv row-tile, y = oc group; one oc
// chunk per wave. x>=512 & y==0 -> pad fills. (Verified R6/R7 structure;
// byte-identical to R3 — held constant to isolate the attn-kernel change.)
// ---------------------------------------------------------------------------
__global__ __launch_bounds__(256) void qkv_prep_kernel(const float* __restrict__ x,
                                                       const float* __restrict__ Wqkv,
                                                       const float* __restrict__ bqkv,
                                                       const float* __restrict__ embk,
                                                       const float* __restrict__ embv,
                                                       const float* __restrict__ Wproj,
                                                       u16* __restrict__ q_bf,
                                                       u16* __restrict__ k_bf,
                                                       u16* __restrict__ vT_bf,
                                                       u16* __restrict__ embk_pad,
                                                       u16* __restrict__ embvT_pad,
                                                       u16* __restrict__ Wproj_bf) {
    const int blk = blockIdx.x;
    const int grp = blockIdx.y;
    const int tid = threadIdx.x;

    if (blk >= 512) {
        if (grp != 0) return;
        const int idx0 = (blk - 512) * 256 + tid;
        const int stride = 64 * 256;
        for (int i = idx0; i < 1088 * CC; i += stride) {
            int r = i >> 6, c = i & 63, d = r - 32;
            embk_pad[i] = (d >= 0 && d < TT) ? f2bf(embk[d * CC + c]) : (u16)0;
        }
        for (int i = idx0; i < CC * 1088; i += stride) {
            int c = i / 1088, col = i - c * 1088, d = col - 32;
            embvT_pad[i] = (d >= 0 && d < TT) ? f2bf(embv[d * CC + c]) : (u16)0;
        }
        for (int i = idx0; i < CC * CC; i += stride) Wproj_bf[i] = f2bf(Wproj[i]);
        return;
    }

    const int w = tid >> 6, lane = tid & 63, quad = lane >> 4, l15 = lane & 15;
    const int row0 = blk * 16;
    const int oc = grp * 4 + w;                 // 0..11
    __shared__ float vt[4][16][17];

    const float* xr = x + (size_t)(row0 + l15) * CC + quad * 8;
    short8 a0 = pack8(xr);
    short8 a1 = pack8(xr + 32);

    const float* wr = Wqkv + (size_t)(oc * 16 + l15) * CC + quad * 8;
    short8 b0 = pack8(wr);
    short8 b1 = pack8(wr + 32);
    f32x4 acc = {0.f, 0.f, 0.f, 0.f};
    acc = MFMA16(a0, b0, acc);
    acc = MFMA16(a1, b1, acc);
    const float bias = bqkv[oc * 16 + l15];

    if (oc < 4) {
        const int c = oc * 16 + l15;
        #pragma unroll
        for (int r = 0; r < 4; ++r)
            q_bf[(size_t)(row0 + quad * 4 + r) * CC + c] = f2bf((acc[r] + bias) * 0.125f);
    } else if (oc < 8) {
        const int c = (oc - 4) * 16 + l15;
        #pragma unroll
        for (int r = 0; r < 4; ++r)
            k_bf[(size_t)(row0 + quad * 4 + r) * CC + c] = f2bf(acc[r] + bias);
    } else {
        #pragma unroll
        for (int r = 0; r < 4; ++r) vt[w][quad * 4 + r][l15] = acc[r] + bias;
        const int c_l = lane >> 2;
        const int tbase = (lane & 3) * 4;
        const int b = row0 >> 10, t0v = row0 & (TT - 1);
        u16 p[4];
        #pragma unroll
        for (int tt2 = 0; tt2 < 4; ++tt2) p[tt2] = f2bf(vt[w][tbase + tt2][c_l]);
        unsigned long long pk = (unsigned long long)p[0] | ((unsigned long long)p[1] << 16)
                              | ((unsigned long long)p[2] << 32) | ((unsigned long long)p[3] << 48);
        *(unsigned long long*)&vT_bf[(size_t)(b * CC + (oc - 8) * 16 + c_l) * TT + t0v + tbase] = pk;
    }
}

// ---------------------------------------------------------------------------
// K2 (R4): one-kernel attention, grid (64, 8), 512 thr (8 waves), wave w
// loops s-tiles st = w, w+8, ...  R3 measured this latency-bound at 43.6us
// with VGPR_Count=64: the compiler couldn't keep the ~20 independent 16B
// loads of a round in flight, serializing ~15 exposed memory latencies.
// R4 fix: __launch_bounds__(512, 2) -> 128-VGPR budget (still 4 waves/SIMD,
// both blocks/CU resident), and ALL of a round's global loads are issued up
// front into statically-indexed registers (rule #20: full unroll) before any
// dependent compute. Math byte-identical to the verified R0 body.
// ---------------------------------------------------------------------------
#define WBSTRIDE 4160   // per-wave LDS: pt(1280) + a2(2304) = 3584; merge 4096

__global__ __launch_bounds__(512, 2) void attn_loop_kernel(const u16* __restrict__ q_bf,
                                                           const u16* __restrict__ k_bf,
                                                           const u16* __restrict__ vT_bf,
                                                           const u16* __restrict__ embk_pad,
                                                           const u16* __restrict__ embvT_pad,
                                                           const u16* __restrict__ Wproj_bf,
                                                           const float* __restrict__ bproj,
                                                           float* __restrict__ out) {
    const int b = blockIdx.y;
    const int tt = 63 - blockIdx.x;               // heavy tiles first
    const int t0 = tt * 16;
    const int nst = (t0 >> 5) + 1;

    const int tid = threadIdx.x;
    const int w = tid >> 6, lane = tid & 63, quad = lane >> 4, l15 = lane & 15;

    __shared__ __align__(16) char wbuf[8][WBSTRIDE];
    __shared__ float lpart[8][16];
    __shared__ float Ls[16];
    __shared__ __align__(16) u16 yA[16 * 64];

    u16* pt = (u16*)(wbuf[w]);                    // 16*40 bf16
    u16* a2 = (u16*)(wbuf[w] + 1280);             // 16*72 bf16 (skewed P)

    f32x4 acc[4];
    #pragma unroll
    for (int nb = 0; nb < 4; ++nb) acc[nb] = (f32x4){0.f, 0.f, 0.f, 0.f};
    float rsum[4] = {0.f, 0.f, 0.f, 0.f};

    // hoisted Q fragments (q pre-scaled by 0.125) — reused across all s-tiles
    const u16* qrow = q_bf + (size_t)((b << 10) + t0 + l15) * CC;
    short8 aq0 = *(const short8*)(qrow + quad * 8);
    short8 aq1 = *(const short8*)(qrow + 32 + quad * 8);

    for (int st = w; st < nst; st += 8) {
        const int s0 = st * 32;
        const int dcol0 = t0 - s0;
        const int dbase = t0 - s0 - 31;

        // ==== issue ALL of this round's global loads up front ====
        const u16* krow0 = k_bf + (size_t)((b << 10) + s0 + l15) * CC;
        const u16* krow1 = k_bf + (size_t)((b << 10) + s0 + 16 + l15) * CC;
        short8 kb00 = *(const short8*)(krow0 + quad * 8);
        short8 kb01 = *(const short8*)(krow0 + 32 + quad * 8);
        short8 kb10 = *(const short8*)(krow1 + quad * 8);
        short8 kb11 = *(const short8*)(krow1 + 32 + quad * 8);

        short8 eb[3][2];
        #pragma unroll
        for (int nb = 0; nb < 3; ++nb) {
            const u16* erow = embk_pad + (size_t)(dbase + 32 + nb * 16 + l15) * CC;
            eb[nb][0] = *(const short8*)(erow + quad * 8);
            eb[nb][1] = *(const short8*)(erow + 32 + quad * 8);
        }

        short8 bv[4];
        #pragma unroll
        for (int nb = 0; nb < 4; ++nb) {
            const u16* vrow = vT_bf + ((size_t)(b * CC + nb * 16 + l15) << 10) + s0;
            bv[nb] = *(const short8*)(vrow + quad * 8);
        }

        short8 be[2][4];
        #pragma unroll
        for (int kk = 0; kk < 2; ++kk)
            #pragma unroll
            for (int nb = 0; nb < 4; ++nb) {
                const u16* erow = embvT_pad + (size_t)(nb * 16 + l15) * 1088 + dcol0 + kk * 32 + quad * 8;
                be[kk][nb] = *(const short8*)erow;
            }

        // ==== content scores: 16x32 tile ====
        f32x4 sc[2];
        {
            f32x4 a = {0.f, 0.f, 0.f, 0.f};
            a = MFMA16(aq0, kb00, a);
            a = MFMA16(aq1, kb01, a);
            sc[0] = a;
        }
        {
            f32x4 a = {0.f, 0.f, 0.f, 0.f};
            a = MFMA16(aq0, kb10, a);
            a = MFMA16(aq1, kb11, a);
            sc[1] = a;
        }

        // ==== relative band: 3 MFMAs kept in C-layout registers ====
        f32x4 bnd[3];
        #pragma unroll
        for (int nb = 0; nb < 3; ++nb) {
            f32x4 a = {0.f, 0.f, 0.f, 0.f};
            a = MFMA16(aq0, eb[nb][0], a);
            a = MFMA16(aq1, eb[nb][1], a);
            bnd[nb] = a;
        }

        // ==== band via cross-lane shuffles + masked p = exp(score) ====
        u16 pb0[4], pb1[4];
        #pragma unroll
        for (int r = 0; r < 4; ++r) {
            const int i = quad * 4 + r;
            const int u0 = 31 + i - l15;
            const int src = (quad << 4) | (u0 & 15);
            const float v0 = __shfl(bnd[0][r], src, 64);
            const float v1 = __shfl(bnd[1][r], src, 64);
            const float v2 = __shfl(bnd[2][r], src, 64);
            const bool hi = (u0 >= 32);
            {   // cb = 0: j = l15
                const float rb = hi ? v2 : v1;
                const int d = t0 - s0 + i - l15;
                float pv = (d >= 0) ? __expf(sc[0][r] + rb) : 0.f;
                pb0[r] = f2bf(pv);
                rsum[r] += bf2f(pb0[r]);
            }
            {   // cb = 1: j = 16+l15
                const float rb = hi ? v1 : v0;
                const int d = t0 - s0 + i - 16 - l15;
                float pv = (d >= 0) ? __expf(sc[1][r] + rb) : 0.f;
                pb1[r] = f2bf(pv);
                rsum[r] += bf2f(pb1[r]);
            }
        }

        // ==== write P: row-major (pt) and skewed (a2); in-wave DS order ====
        u32x4 z = {0u, 0u, 0u, 0u};
        #pragma unroll
        for (int e = 0; e < 3; ++e) {              // 144 u32x4 = 16*72 u16
            int idx = lane + e * 64;
            if (idx < 144) ((u32x4*)a2)[idx] = z;
        }
        #pragma unroll
        for (int r = 0; r < 4; ++r) {
            const int i = quad * 4 + r;
            pt[i * 40 + l15] = pb0[r];
            pt[i * 40 + 16 + l15] = pb1[r];
            a2[i * 72 + (32 + i - l15)] = pb0[r];
            a2[i * 72 + (16 + i - l15)] = pb1[r];
        }

        // ==== y1 += P @ V ====
        short8 aP = *(const short8*)(pt + l15 * 40 + quad * 8);
        #pragma unroll
        for (int nb = 0; nb < 4; ++nb)
            acc[nb] = MFMA16(aP, bv[nb], acc[nb]);

        // ==== y2 += skew(P) @ embv band ====
        #pragma unroll
        for (int kk = 0; kk < 2; ++kk) {
            short8 a2f = *(const short8*)(a2 + l15 * 72 + kk * 32 + quad * 8);
            #pragma unroll
            for (int nb = 0; nb < 4; ++nb)
                acc[nb] = MFMA16(a2f, be[kk][nb], acc[nb]);
        }
    }

    // ---- per-wave row-sum reduction ----
    #pragma unroll
    for (int msk = 1; msk < 16; msk <<= 1)
        #pragma unroll
        for (int r = 0; r < 4; ++r) rsum[r] += __shfl_xor(rsum[r], msk, 64);
    if (l15 == 0) {
        #pragma unroll
        for (int r = 0; r < 4; ++r) lpart[w][quad * 4 + r] = rsum[r];
    }

    // ---- wave partial Y -> unioned per-wave LDS region ----
    float* ypw = (float*)(wbuf[w]);
    #pragma unroll
    for (int nb = 0; nb < 4; ++nb)
        #pragma unroll
        for (int r = 0; r < 4; ++r)
            ypw[(quad * 4 + r) * 64 + nb * 16 + l15] = acc[nb][r];
    __syncthreads();

    // ---- merge 8 wave partials (threads 0..255 own the 16x64 tile) ----
    const int i = tid >> 4, c0 = (tid * 4) & 63;
    float4 Y = {0.f, 0.f, 0.f, 0.f};
    if (tid < 256) {
        #pragma unroll
        for (int ww = 0; ww < 8; ++ww) {
            const float* src = (const float*)(wbuf[ww]);
            Y.x += src[i * 64 + c0];
            Y.y += src[i * 64 + c0 + 1];
            Y.z += src[i * 64 + c0 + 2];
            Y.w += src[i * 64 + c0 + 3];
        }
        if (tid < 16) {
            float L = 0.f;
            #pragma unroll
            for (int ww = 0; ww < 8; ++ww) L += lpart[ww][tid];
            Ls[tid] = L;
        }
    }
    __syncthreads();

    // ---- normalize + bf16 pack ----
    if (tid < 256) {
        const float inv = 1.0f / Ls[i];
        u16 y4[4] = { f2bf(Y.x * inv), f2bf(Y.y * inv), f2bf(Y.z * inv), f2bf(Y.w * inv) };
        *(unsigned long long*)&yA[i * 64 + c0] =
            (unsigned long long)y4[0] | ((unsigned long long)y4[1] << 16)
          | ((unsigned long long)y4[2] << 32) | ((unsigned long long)y4[3] << 48);
    }
    __syncthreads();

    // ---- proj epilogue: waves 0..3 -> output cols w*16 .. +15 ----
    if (w < 4) {
        short8 a0 = *(const short8*)(yA + l15 * 64 + quad * 8);
        short8 a1 = *(const short8*)(yA + l15 * 64 + 32 + quad * 8);
        const u16* wrow = Wproj_bf + (size_t)(w * 16 + l15) * CC;
        short8 wb0 = *(const short8*)(wrow + quad * 8);
        short8 wb1 = *(const short8*)(wrow + 32 + quad * 8);
        f32x4 o = {0.f, 0.f, 0.f, 0.f};
        o = MFMA16(a0, wb0, o);
        o = MFMA16(a1, wb1, o);
        const float bias = bproj[w * 16 + l15];
        #pragma unroll
        for (int r = 0; r < 4; ++r)
            out[(size_t)((b << 10) + t0 + quad * 4 + r) * CC + w * 16 + l15] = o[r] + bias;
    }
}

// ===========================================================================
// Fallback path (round-1 verified fp32 kernels) — used if ws_size < needed.
// ===========================================================================
__global__ __launch_bounds__(192) void qkv_kernel(const float* __restrict__ x,
                                                  const float* __restrict__ Wqkv,
                                                  const float* __restrict__ bqkv,
                                                  float* __restrict__ qkv) {
    __shared__ __align__(16) float xs[CC];
    const int row = blockIdx.x;
    const int j = threadIdx.x;
    if (j < CC) xs[j] = x[row * CC + j];
    __syncthreads();
    const float* w = Wqkv + j * CC;
    float acc = bqkv[j];
    #pragma unroll
    for (int c = 0; c < CC; c += 4) {
        float4 wq = *(const float4*)(w + c);
        float4 xq = *(const float4*)(xs + c);
        acc += wq.x * xq.x + wq.y * xq.y + wq.z * xq.z + wq.w * xq.w;
    }
    qkv[row * 192 + j] = acc;
}

__global__ __launch_bounds__(256) void attn_kernel(const float* __restrict__ qkv,
                                                   const float* __restrict__ embk,
                                                   const float* __restrict__ embv,
                                                   const float* __restrict__ Wproj,
                                                   const float* __restrict__ bproj,
                                                   float* __restrict__ out) {
    __shared__ __align__(16) float qs[CC];
    __shared__ __align__(16) float sc[TT];
    __shared__ float red[256];
    __shared__ float yred[4][CC];
    const int bt = blockIdx.x;
    const int b = bt >> 10, t = bt & (TT - 1);
    const int tid = threadIdx.x;
    if (tid < CC) qs[tid] = qkv[bt * 192 + tid];
    __syncthreads();
    float lmax = -1e30f;
    for (int s = tid; s <= t; s += 256) {
        const float* krow = qkv + (b * TT + s) * 192 + 64;
        const float* erow = embk + (t - s) * CC;
        float acc = 0.f;
        #pragma unroll
        for (int c = 0; c < CC; c += 4) {
            float4 kq = *(const float4*)(krow + c);
            float4 eq = *(const float4*)(erow + c);
            float4 qq = *(const float4*)(qs + c);
            acc += qq.x * (kq.x + eq.x) + qq.y * (kq.y + eq.y)
                 + qq.z * (kq.z + eq.z) + qq.w * (kq.w + eq.w);
        }
        acc *= 0.125f;
        sc[s] = acc;
        lmax = fmaxf(lmax, acc);
    }
    red[tid] = lmax; __syncthreads();
    for (int off = 128; off > 0; off >>= 1) { if (tid < off) red[tid] = fmaxf(red[tid], red[tid + off]); __syncthreads(); }
    const float m = red[0]; __syncthreads();
    float lsum = 0.f;
    for (int s = tid; s <= t; s += 256) { float e = __expf(sc[s] - m); sc[s] = e; lsum += e; }
    red[tid] = lsum; __syncthreads();
    for (int off = 128; off > 0; off >>= 1) { if (tid < off) red[tid] += red[tid + off]; __syncthreads(); }
    const float inv = 1.0f / red[0]; __syncthreads();
    const int c = tid & 63, g = tid >> 6;
    float acc = 0.f;
    for (int s = g; s <= t; s += 4) {
        float p = sc[s];
        float vv = qkv[(b * TT + s) * 192 + 128 + c];
        float ev = embv[(t - s) * CC + c];
        acc += p * (vv + ev);
    }
    yred[g][c] = acc * inv;
    __syncthreads();
    if (tid < CC) qs[tid] = yred[0][tid] + yred[1][tid] + yred[2][tid] + yred[3][tid];
    __syncthreads();
    if (tid < CC) {
        const float* w = Wproj + tid * CC;
        float o = bproj[tid];
        #pragma unroll
        for (int cc2 = 0; cc2 < CC; cc2 += 4) {
            float4 wq = *(const float4*)(w + cc2);
            float4 yq = *(const float4*)(qs + cc2);
            o += wq.x * yq.x + wq.y * yq.y + wq.z * yq.z + wq.w * yq.w;
        }
        out[bt * CC + tid] = o;
    }
}

extern "C" void kernel_launch(void* const* d_in, const int* in_sizes, int n_in,
                              void* d_out, int out_size, void* d_ws, size_t ws_size,
                              hipStream_t stream) {
    const float* x     = (const float*)d_in[0];
    const float* Wqkv  = (const float*)d_in[1];
    const float* bqkv  = (const float*)d_in[2];
    const float* embk  = (const float*)d_in[3];
    const float* embv  = (const float*)d_in[4];
    const float* Wproj = (const float*)d_in[5];
    const float* bproj = (const float*)d_in[6];
    float* out = (float*)d_out;

    if (ws_size < WS_NEED) {
        float* qkv = (float*)d_ws;
        qkv_kernel<<<BB * TT, 192, 0, stream>>>(x, Wqkv, bqkv, qkv);
        attn_kernel<<<BB * TT, 256, 0, stream>>>(qkv, embk, embv, Wproj, bproj, out);
        return;
    }

    char* ws = (char*)d_ws;
    u16* q_bf       = (u16*)(ws + OFF_QBF);
    u16* k_bf       = (u16*)(ws + OFF_KBF);
    u16* vT_bf      = (u16*)(ws + OFF_VT);
    u16* embk_pad   = (u16*)(ws + OFF_EKP);
    u16* embvT_pad  = (u16*)(ws + OFF_EVT);
    u16* Wproj_bf   = (u16*)(ws + OFF_WPROJ);

    qkv_prep_kernel<<<dim3(576, 3), 256, 0, stream>>>(x, Wqkv, bqkv, embk, embv, Wproj,
                                                      q_bf, k_bf, vT_bf, embk_pad, embvT_pad, Wproj_bf);
    attn_loop_kernel<<<dim3(64, 8), 512, 0, stream>>>(q_bf, k_bf, vT_bf, embk_pad, embvT_pad,
                                                      Wproj_bf, bproj, out);
}

// Round 5
// 104.914 us; speedup vs baseline: 1.1291x; 1.1197x over previous
//
#include <hip/hip_runtime.h>
#include <math.h>

#define BB 8
#define TT 1024
#define CC 64

typedef float f32x4 __attribute__((ext_vector_type(4)));
typedef short short8 __attribute__((ext_vector_type(8)));
typedef unsigned int u32x4 __attribute__((ext_vector_type(4)));
typedef unsigned short u16;

static __device__ __forceinline__ u16 f2bf(float f) {
    union { float f; unsigned int u; } v; v.f = f;
    unsigned int r = v.u + 0x7fffu + ((v.u >> 16) & 1u);
    return (u16)(r >> 16);
}
static __device__ __forceinline__ float bf2f(u16 h) {
    union { unsigned int u; float f; } v; v.u = ((unsigned int)h) << 16; return v.f;
}
static __device__ __forceinline__ short8 pack8(const float* p) {
    float4 a = *(const float4*)p;
    float4 b = *(const float4*)(p + 4);
    short8 r;
    r[0] = (short)f2bf(a.x); r[1] = (short)f2bf(a.y); r[2] = (short)f2bf(a.z); r[3] = (short)f2bf(a.w);
    r[4] = (short)f2bf(b.x); r[5] = (short)f2bf(b.y); r[6] = (short)f2bf(b.z); r[7] = (short)f2bf(b.w);
    return r;
}

#define MFMA16(a, b, c) __builtin_amdgcn_mfma_f32_16x16x32_bf16((a), (b), (c), 0, 0, 0)

// Workspace layout (bytes).
// R5: vT and embvT re-tiled into 8-wide panels so the PV/y2 fragment loads
// are lane-contiguous (R4 post-mortem: the old layouts cost 64 cachelines
// per wave-load instruction — ~75% of ~5M line transactions/launch, the
// measured 44us). New layouts:
//   vT2   : [b][t/8][c][8]      (same 1MB)
//   embvT2: [(d+32)/8][c][8]    (same 139264B)
#define OFF_QBF      ((size_t)0)             // q pre-scaled by 0.125
#define OFF_KBF      ((size_t)1048576)
#define OFF_VT       ((size_t)2097152)       // vT2
#define OFF_EKP      ((size_t)3145728)       // 1088*64 bf16 (rows d=-32..1055)
#define OFF_EVT      ((size_t)3284992)       // embvT2
#define OFF_WPROJ    ((size_t)3424256)       // 64*64 bf16
#define WS_NEED      ((size_t)3432448)

// ---------------------------------------------------------------------------
// K1: qkv + prep. Grid (576, 3): x<512 -> qkv row-tile, y = oc group; one oc
// chunk per wave. x>=512 & y==0 -> pad fills. Only the vT write and embvT
// fill use the new panel indexing; all math identical to the verified body.
// ---------------------------------------------------------------------------
__global__ __launch_bounds__(256) void qkv_prep_kernel(const float* __restrict__ x,
                                                       const float* __restrict__ Wqkv,
                                                       const float* __restrict__ bqkv,
                                                       const float* __restrict__ embk,
                                                       const float* __restrict__ embv,
                                                       const float* __restrict__ Wproj,
                                                       u16* __restrict__ q_bf,
                                                       u16* __restrict__ k_bf,
                                                       u16* __restrict__ vT_bf,
                                                       u16* __restrict__ embk_pad,
                                                       u16* __restrict__ embvT_pad,
                                                       u16* __restrict__ Wproj_bf) {
    const int blk = blockIdx.x;
    const int grp = blockIdx.y;
    const int tid = threadIdx.x;

    if (blk >= 512) {
        if (grp != 0) return;
        const int idx0 = (blk - 512) * 256 + tid;
        const int stride = 64 * 256;
        for (int i = idx0; i < 1088 * CC; i += stride) {
            int r = i >> 6, c = i & 63, d = r - 32;
            embk_pad[i] = (d >= 0 && d < TT) ? f2bf(embk[d * CC + c]) : (u16)0;
        }
        // embvT2[dp][c][e]: linear i = dp*512 + c*8 + e; d = dp*8 + e - 32
        for (int i = idx0; i < CC * 1088; i += stride) {
            int dp = i >> 9, c = (i >> 3) & 63, e = i & 7;
            int d = dp * 8 + e - 32;
            embvT_pad[i] = (d >= 0 && d < TT) ? f2bf(embv[d * CC + c]) : (u16)0;
        }
        for (int i = idx0; i < CC * CC; i += stride) Wproj_bf[i] = f2bf(Wproj[i]);
        return;
    }

    const int w = tid >> 6, lane = tid & 63, quad = lane >> 4, l15 = lane & 15;
    const int row0 = blk * 16;
    const int oc = grp * 4 + w;                 // 0..11
    __shared__ float vt[4][16][17];

    const float* xr = x + (size_t)(row0 + l15) * CC + quad * 8;
    short8 a0 = pack8(xr);
    short8 a1 = pack8(xr + 32);

    const float* wr = Wqkv + (size_t)(oc * 16 + l15) * CC + quad * 8;
    short8 b0 = pack8(wr);
    short8 b1 = pack8(wr + 32);
    f32x4 acc = {0.f, 0.f, 0.f, 0.f};
    acc = MFMA16(a0, b0, acc);
    acc = MFMA16(a1, b1, acc);
    const float bias = bqkv[oc * 16 + l15];

    if (oc < 4) {
        const int c = oc * 16 + l15;
        #pragma unroll
        for (int r = 0; r < 4; ++r)
            q_bf[(size_t)(row0 + quad * 4 + r) * CC + c] = f2bf((acc[r] + bias) * 0.125f);
    } else if (oc < 8) {
        const int c = (oc - 4) * 16 + l15;
        #pragma unroll
        for (int r = 0; r < 4; ++r)
            k_bf[(size_t)(row0 + quad * 4 + r) * CC + c] = f2bf(acc[r] + bias);
    } else {
        #pragma unroll
        for (int r = 0; r < 4; ++r) vt[w][quad * 4 + r][l15] = acc[r] + bias;
        const int c_l = lane >> 2;
        const int tbase = (lane & 3) * 4;
        const int b = row0 >> 10, t0v = row0 & (TT - 1);
        u16 p[4];
        #pragma unroll
        for (int tt2 = 0; tt2 < 4; ++tt2) p[tt2] = f2bf(vt[w][tbase + tt2][c_l]);
        unsigned long long pk = (unsigned long long)p[0] | ((unsigned long long)p[1] << 16)
                              | ((unsigned long long)p[2] << 32) | ((unsigned long long)p[3] << 48);
        // vT2[b][sp][c][e0..e0+3]: t = t0v + tbase + 0..3 stays inside one
        // 8-panel because tbase % 4 == 0 and t0v % 16 == 0.
        const int c = (oc - 8) * 16 + c_l;
        const int sp = (t0v + tbase) >> 3;
        const int e0 = tbase & 7;                 // 0 or 4
        *(unsigned long long*)&vT_bf[(((size_t)(b * 128 + sp) * CC + c) << 3) + e0] = pk;
    }
}

// ---------------------------------------------------------------------------
// K2 (R5): one-kernel attention, grid (64, 8), 512 thr (8 waves), wave w
// loops s-tiles st = w, w+8, ...  R4 post-mortem: latency-looking profile was
// actually VMEM-transaction-bound — vT/embvT fragment gathers at 2KB/2176B
// lane stride touched 64 lines per instruction. R5 consumes the panelized
// vT2/embvT2 layouts: 16 consecutive lanes read 256B contiguous (8 lines
// per instruction). K/embk row-gathers (16 lines, fully dense) unchanged.
// Math byte-identical to the verified R0 body.
// ---------------------------------------------------------------------------
#define WBSTRIDE 4160   // per-wave LDS: pt(1280) + a2(2304) = 3584; merge 4096

__global__ __launch_bounds__(512, 2) void attn_loop_kernel(const u16* __restrict__ q_bf,
                                                           const u16* __restrict__ k_bf,
                                                           const u16* __restrict__ vT_bf,
                                                           const u16* __restrict__ embk_pad,
                                                           const u16* __restrict__ embvT_pad,
                                                           const u16* __restrict__ Wproj_bf,
                                                           const float* __restrict__ bproj,
                                                           float* __restrict__ out) {
    const int b = blockIdx.y;
    const int tt = 63 - blockIdx.x;               // heavy tiles first
    const int t0 = tt * 16;
    const int nst = (t0 >> 5) + 1;

    const int tid = threadIdx.x;
    const int w = tid >> 6, lane = tid & 63, quad = lane >> 4, l15 = lane & 15;

    __shared__ __align__(16) char wbuf[8][WBSTRIDE];
    __shared__ float lpart[8][16];
    __shared__ float Ls[16];
    __shared__ __align__(16) u16 yA[16 * 64];

    u16* pt = (u16*)(wbuf[w]);                    // 16*40 bf16
    u16* a2 = (u16*)(wbuf[w] + 1280);             // 16*72 bf16 (skewed P)

    f32x4 acc[4];
    #pragma unroll
    for (int nb = 0; nb < 4; ++nb) acc[nb] = (f32x4){0.f, 0.f, 0.f, 0.f};
    float rsum[4] = {0.f, 0.f, 0.f, 0.f};

    // hoisted Q fragments (q pre-scaled by 0.125) — reused across all s-tiles
    const u16* qrow = q_bf + (size_t)((b << 10) + t0 + l15) * CC;
    short8 aq0 = *(const short8*)(qrow + quad * 8);
    short8 aq1 = *(const short8*)(qrow + 32 + quad * 8);

    for (int st = w; st < nst; st += 8) {
        const int s0 = st * 32;
        const int dcol0 = t0 - s0;
        const int dbase = t0 - s0 - 31;

        // ==== issue ALL of this round's global loads up front ====
        const u16* krow0 = k_bf + (size_t)((b << 10) + s0 + l15) * CC;
        const u16* krow1 = k_bf + (size_t)((b << 10) + s0 + 16 + l15) * CC;
        short8 kb00 = *(const short8*)(krow0 + quad * 8);
        short8 kb01 = *(const short8*)(krow0 + 32 + quad * 8);
        short8 kb10 = *(const short8*)(krow1 + quad * 8);
        short8 kb11 = *(const short8*)(krow1 + 32 + quad * 8);

        short8 eb[3][2];
        #pragma unroll
        for (int nb = 0; nb < 3; ++nb) {
            const u16* erow = embk_pad + (size_t)(dbase + 32 + nb * 16 + l15) * CC;
            eb[nb][0] = *(const short8*)(erow + quad * 8);
            eb[nb][1] = *(const short8*)(erow + 32 + quad * 8);
        }

        // vT2[b][s0/8 + quad][c][0..7]: lane-contiguous panels
        short8 bv[4];
        #pragma unroll
        for (int nb = 0; nb < 4; ++nb) {
            const u16* vp = vT_bf + (((size_t)(b * 128 + (s0 >> 3) + quad) * CC + nb * 16 + l15) << 3);
            bv[nb] = *(const short8*)vp;
        }

        // embvT2[(dcol0+kk*32)/8 + quad][c][0..7]
        short8 be[2][4];
        #pragma unroll
        for (int kk = 0; kk < 2; ++kk) {
            const int dp0 = (dcol0 + kk * 32) >> 3;
            #pragma unroll
            for (int nb = 0; nb < 4; ++nb) {
                const u16* ep = embvT_pad + (((size_t)(dp0 + quad) * CC + nb * 16 + l15) << 3);
                be[kk][nb] = *(const short8*)ep;
            }
        }

        // ==== content scores: 16x32 tile ====
        f32x4 sc[2];
        {
            f32x4 a = {0.f, 0.f, 0.f, 0.f};
            a = MFMA16(aq0, kb00, a);
            a = MFMA16(aq1, kb01, a);
            sc[0] = a;
        }
        {
            f32x4 a = {0.f, 0.f, 0.f, 0.f};
            a = MFMA16(aq0, kb10, a);
            a = MFMA16(aq1, kb11, a);
            sc[1] = a;
        }

        // ==== relative band: 3 MFMAs kept in C-layout registers ====
        f32x4 bnd[3];
        #pragma unroll
        for (int nb = 0; nb < 3; ++nb) {
            f32x4 a = {0.f, 0.f, 0.f, 0.f};
            a = MFMA16(aq0, eb[nb][0], a);
            a = MFMA16(aq1, eb[nb][1], a);
            bnd[nb] = a;
        }

        // ==== band via cross-lane shuffles + masked p = exp(score) ====
        u16 pb0[4], pb1[4];
        #pragma unroll
        for (int r = 0; r < 4; ++r) {
            const int i = quad * 4 + r;
            const int u0 = 31 + i - l15;
            const int src = (quad << 4) | (u0 & 15);
            const float v0 = __shfl(bnd[0][r], src, 64);
            const float v1 = __shfl(bnd[1][r], src, 64);
            const float v2 = __shfl(bnd[2][r], src, 64);
            const bool hi = (u0 >= 32);
            {   // cb = 0: j = l15
                const float rb = hi ? v2 : v1;
                const int d = t0 - s0 + i - l15;
                float pv = (d >= 0) ? __expf(sc[0][r] + rb) : 0.f;
                pb0[r] = f2bf(pv);
                rsum[r] += bf2f(pb0[r]);
            }
            {   // cb = 1: j = 16+l15
                const float rb = hi ? v1 : v0;
                const int d = t0 - s0 + i - 16 - l15;
                float pv = (d >= 0) ? __expf(sc[1][r] + rb) : 0.f;
                pb1[r] = f2bf(pv);
                rsum[r] += bf2f(pb1[r]);
            }
        }

        // ==== write P: row-major (pt) and skewed (a2); in-wave DS order ====
        u32x4 z = {0u, 0u, 0u, 0u};
        #pragma unroll
        for (int e = 0; e < 3; ++e) {              // 144 u32x4 = 16*72 u16
            int idx = lane + e * 64;
            if (idx < 144) ((u32x4*)a2)[idx] = z;
        }
        #pragma unroll
        for (int r = 0; r < 4; ++r) {
            const int i = quad * 4 + r;
            pt[i * 40 + l15] = pb0[r];
            pt[i * 40 + 16 + l15] = pb1[r];
            a2[i * 72 + (32 + i - l15)] = pb0[r];
            a2[i * 72 + (16 + i - l15)] = pb1[r];
        }

        // ==== y1 += P @ V ====
        short8 aP = *(const short8*)(pt + l15 * 40 + quad * 8);
        #pragma unroll
        for (int nb = 0; nb < 4; ++nb)
            acc[nb] = MFMA16(aP, bv[nb], acc[nb]);

        // ==== y2 += skew(P) @ embv band ====
        #pragma unroll
        for (int kk = 0; kk < 2; ++kk) {
            short8 a2f = *(const short8*)(a2 + l15 * 72 + kk * 32 + quad * 8);
            #pragma unroll
            for (int nb = 0; nb < 4; ++nb)
                acc[nb] = MFMA16(a2f, be[kk][nb], acc[nb]);
        }
    }

    // ---- per-wave row-sum reduction ----
    #pragma unroll
    for (int msk = 1; msk < 16; msk <<= 1)
        #pragma unroll
        for (int r = 0; r < 4; ++r) rsum[r] += __shfl_xor(rsum[r], msk, 64);
    if (l15 == 0) {
        #pragma unroll
        for (int r = 0; r < 4; ++r) lpart[w][quad * 4 + r] = rsum[r];
    }

    // ---- wave partial Y -> unioned per-wave LDS region ----
    float* ypw = (float*)(wbuf[w]);
    #pragma unroll
    for (int nb = 0; nb < 4; ++nb)
        #pragma unroll
        for (int r = 0; r < 4; ++r)
            ypw[(quad * 4 + r) * 64 + nb * 16 + l15] = acc[nb][r];
    __syncthreads();

    // ---- merge 8 wave partials (threads 0..255 own the 16x64 tile) ----
    const int i = tid >> 4, c0 = (tid * 4) & 63;
    float4 Y = {0.f, 0.f, 0.f, 0.f};
    if (tid < 256) {
        #pragma unroll
        for (int ww = 0; ww < 8; ++ww) {
            const float* src = (const float*)(wbuf[ww]);
            Y.x += src[i * 64 + c0];
            Y.y += src[i * 64 + c0 + 1];
            Y.z += src[i * 64 + c0 + 2];
            Y.w += src[i * 64 + c0 + 3];
        }
        if (tid < 16) {
            float L = 0.f;
            #pragma unroll
            for (int ww = 0; ww < 8; ++ww) L += lpart[ww][tid];
            Ls[tid] = L;
        }
    }
    __syncthreads();

    // ---- normalize + bf16 pack ----
    if (tid < 256) {
        const float inv = 1.0f / Ls[i];
        u16 y4[4] = { f2bf(Y.x * inv), f2bf(Y.y * inv), f2bf(Y.z * inv), f2bf(Y.w * inv) };
        *(unsigned long long*)&yA[i * 64 + c0] =
            (unsigned long long)y4[0] | ((unsigned long long)y4[1] << 16)
          | ((unsigned long long)y4[2] << 32) | ((unsigned long long)y4[3] << 48);
    }
    __syncthreads();

    // ---- proj epilogue: waves 0..3 -> output cols w*16 .. +15 ----
    if (w < 4) {
        short8 a0 = *(const short8*)(yA + l15 * 64 + quad * 8);
        short8 a1 = *(const short8*)(yA + l15 * 64 + 32 + quad * 8);
        const u16* wrow = Wproj_bf + (size_t)(w * 16 + l15) * CC;
        short8 wb0 = *(const short8*)(wrow + quad * 8);
        short8 wb1 = *(const short8*)(wrow + 32 + quad * 8);
        f32x4 o = {0.f, 0.f, 0.f, 0.f};
        o = MFMA16(a0, wb0, o);
        o = MFMA16(a1, wb1, o);
        const float bias = bproj[w * 16 + l15];
        #pragma unroll
        for (int r = 0; r < 4; ++r)
            out[(size_t)((b << 10) + t0 + quad * 4 + r) * CC + w * 16 + l15] = o[r] + bias;
    }
}

// ===========================================================================
// Fallback path (round-1 verified fp32 kernels) — used if ws_size < needed.
// ===========================================================================
__global__ __launch_bounds__(192) void qkv_kernel(const float* __restrict__ x,
                                                  const float* __restrict__ Wqkv,
                                                  const float* __restrict__ bqkv,
                                                  float* __restrict__ qkv) {
    __shared__ __align__(16) float xs[CC];
    const int row = blockIdx.x;
    const int j = threadIdx.x;
    if (j < CC) xs[j] = x[row * CC + j];
    __syncthreads();
    const float* w = Wqkv + j * CC;
    float acc = bqkv[j];
    #pragma unroll
    for (int c = 0; c < CC; c += 4) {
        float4 wq = *(const float4*)(w + c);
        float4 xq = *(const float4*)(xs + c);
        acc += wq.x * xq.x + wq.y * xq.y + wq.z * xq.z + wq.w * xq.w;
    }
    qkv[row * 192 + j] = acc;
}

__global__ __launch_bounds__(256) void attn_kernel(const float* __restrict__ qkv,
                                                   const float* __restrict__ embk,
                                                   const float* __restrict__ embv,
                                                   const float* __restrict__ Wproj,
                                                   const float* __restrict__ bproj,
                                                   float* __restrict__ out) {
    __shared__ __align__(16) float qs[CC];
    __shared__ __align__(16) float sc[TT];
    __shared__ float red[256];
    __shared__ float yred[4][CC];
    const int bt = blockIdx.x;
    const int b = bt >> 10, t = bt & (TT - 1);
    const int tid = threadIdx.x;
    if (tid < CC) qs[tid] = qkv[bt * 192 + tid];
    __syncthreads();
    float lmax = -1e30f;
    for (int s = tid; s <= t; s += 256) {
        const float* krow = qkv + (b * TT + s) * 192 + 64;
        const float* erow = embk + (t - s) * CC;
        float acc = 0.f;
        #pragma unroll
        for (int c = 0; c < CC; c += 4) {
            float4 kq = *(const float4*)(krow + c);
            float4 eq = *(const float4*)(erow + c);
            float4 qq = *(const float4*)(qs + c);
            acc += qq.x * (kq.x + eq.x) + qq.y * (kq.y + eq.y)
                 + qq.z * (kq.z + eq.z) + qq.w * (kq.w + eq.w);
        }
        acc *= 0.125f;
        sc[s] = acc;
        lmax = fmaxf(lmax, acc);
    }
    red[tid] = lmax; __syncthreads();
    for (int off = 128; off > 0; off >>= 1) { if (tid < off) red[tid] = fmaxf(red[tid], red[tid + off]); __syncthreads(); }
    const float m = red[0]; __syncthreads();
    float lsum = 0.f;
    for (int s = tid; s <= t; s += 256) { float e = __expf(sc[s] - m); sc[s] = e; lsum += e; }
    red[tid] = lsum; __syncthreads();
    for (int off = 128; off > 0; off >>= 1) { if (tid < off) red[tid] += red[tid + off]; __syncthreads(); }
    const float inv = 1.0f / red[0]; __syncthreads();
    const int c = tid & 63, g = tid >> 6;
    float acc = 0.f;
    for (int s = g; s <= t; s += 4) {
        float p = sc[s];
        float vv = qkv[(b * TT + s) * 192 + 128 + c];
        float ev = embv[(t - s) * CC + c];
        acc += p * (vv + ev);
    }
    yred[g][c] = acc * inv;
    __syncthreads();
    if (tid < CC) qs[tid] = yred[0][tid] + yred[1][tid] + yred[2][tid] + yred[3][tid];
    __syncthreads();
    if (tid < CC) {
        const float* w = Wproj + tid * CC;
        float o = bproj[tid];
        #pragma unroll
        for (int cc2 = 0; cc2 < CC; cc2 += 4) {
            float4 wq = *(const float4*)(w + cc2);
            float4 yq = *(const float4*)(qs + cc2);
            o += wq.x * yq.x + wq.y * yq.y + wq.z * yq.z + wq.w * yq.w;
        }
        out[bt * CC + tid] = o;
    }
}

extern "C" void kernel_launch(void* const* d_in, const int* in_sizes, int n_in,
                              void* d_out, int out_size, void* d_ws, size_t ws_size,
                              hipStream_t stream) {
    const float* x     = (const float*)d_in[0];
    const float* Wqkv  = (const float*)d_in[1];
    const float* bqkv  = (const float*)d_in[2];
    const float* embk  = (const float*)d_in[3];
    const float* embv  = (const float*)d_in[4];
    const float* Wproj = (const float*)d_in[5];
    const float* bproj = (const float*)d_in[6];
    float* out = (float*)d_out;

    if (ws_size < WS_NEED) {
        float* qkv = (float*)d_ws;
        qkv_kernel<<<BB * TT, 192, 0, stream>>>(x, Wqkv, bqkv, qkv);
        attn_kernel<<<BB * TT, 256, 0, stream>>>(qkv, embk, embv, Wproj, bproj, out);
        return;
    }

    char* ws = (char*)d_ws;
    u16* q_bf       = (u16*)(ws + OFF_QBF);
    u16* k_bf       = (u16*)(ws + OFF_KBF);
    u16* vT_bf      = (u16*)(ws + OFF_VT);
    u16* embk_pad   = (u16*)(ws + OFF_EKP);
    u16* embvT_pad  = (u16*)(ws + OFF_EVT);
    u16* Wproj_bf   = (u16*)(ws + OFF_WPROJ);

    qkv_prep_kernel<<<dim3(576, 3), 256, 0, stream>>>(x, Wqkv, bqkv, embk, embv, Wproj,
                                                      q_bf, k_bf, vT_bf, embk_pad, embvT_pad, Wproj_bf);
    attn_loop_kernel<<<dim3(64, 8), 512, 0, stream>>>(q_bf, k_bf, vT_bf, embk_pad, embvT_pad,
                                                      Wproj_bf, bproj, out);
}

// Round 6
// 91.549 us; speedup vs baseline: 1.2939x; 1.1460x over previous
//
#include <hip/hip_runtime.h>
#include <math.h>

#define BB 8
#define TT 1024
#define CC 64

typedef float f32x4 __attribute__((ext_vector_type(4)));
typedef short short8 __attribute__((ext_vector_type(8)));
typedef unsigned int u32x4 __attribute__((ext_vector_type(4)));
typedef unsigned short u16;

static __device__ __forceinline__ u16 f2bf(float f) {
    union { float f; unsigned int u; } v; v.f = f;
    unsigned int r = v.u + 0x7fffu + ((v.u >> 16) & 1u);
    return (u16)(r >> 16);
}
static __device__ __forceinline__ float bf2f(u16 h) {
    union { unsigned int u; float f; } v; v.u = ((unsigned int)h) << 16; return v.f;
}
static __device__ __forceinline__ short8 pack8(const float* p) {
    float4 a = *(const float4*)p;
    float4 b = *(const float4*)(p + 4);
    short8 r;
    r[0] = (short)f2bf(a.x); r[1] = (short)f2bf(a.y); r[2] = (short)f2bf(a.z); r[3] = (short)f2bf(a.w);
    r[4] = (short)f2bf(b.x); r[5] = (short)f2bf(b.y); r[6] = (short)f2bf(b.z); r[7] = (short)f2bf(b.w);
    return r;
}

#define MFMA16(a, b, c) __builtin_amdgcn_mfma_f32_16x16x32_bf16((a), (b), (c), 0, 0, 0)

// Workspace layout (bytes). Panelized vT2/embvT2 (R5, verified):
//   vT2   : [b][t/8][c][8]
//   embvT2: [(d+32)/8][c][8]
#define OFF_QBF      ((size_t)0)             // q pre-scaled by 0.125
#define OFF_KBF      ((size_t)1048576)
#define OFF_VT       ((size_t)2097152)       // vT2
#define OFF_EKP      ((size_t)3145728)       // 1088*64 bf16 (rows d=-32..1055)
#define OFF_EVT      ((size_t)3284992)       // embvT2
#define OFF_WPROJ    ((size_t)3424256)       // 64*64 bf16
#define WS_NEED      ((size_t)3432448)

// ---------------------------------------------------------------------------
// K1: qkv + prep. Grid (576, 3). Byte-identical to R5 (held constant).
// ---------------------------------------------------------------------------
__global__ __launch_bounds__(256) void qkv_prep_kernel(const float* __restrict__ x,
                                                       const float* __restrict__ Wqkv,
                                                       const float* __restrict__ bqkv,
                                                       const float* __restrict__ embk,
                                                       const float* __restrict__ embv,
                                                       const float* __restrict__ Wproj,
                                                       u16* __restrict__ q_bf,
                                                       u16* __restrict__ k_bf,
                                                       u16* __restrict__ vT_bf,
                                                       u16* __restrict__ embk_pad,
                                                       u16* __restrict__ embvT_pad,
                                                       u16* __restrict__ Wproj_bf) {
    const int blk = blockIdx.x;
    const int grp = blockIdx.y;
    const int tid = threadIdx.x;

    if (blk >= 512) {
        if (grp != 0) return;
        const int idx0 = (blk - 512) * 256 + tid;
        const int stride = 64 * 256;
        for (int i = idx0; i < 1088 * CC; i += stride) {
            int r = i >> 6, c = i & 63, d = r - 32;
            embk_pad[i] = (d >= 0 && d < TT) ? f2bf(embk[d * CC + c]) : (u16)0;
        }
        // embvT2[dp][c][e]: linear i = dp*512 + c*8 + e; d = dp*8 + e - 32
        for (int i = idx0; i < CC * 1088; i += stride) {
            int dp = i >> 9, c = (i >> 3) & 63, e = i & 7;
            int d = dp * 8 + e - 32;
            embvT_pad[i] = (d >= 0 && d < TT) ? f2bf(embv[d * CC + c]) : (u16)0;
        }
        for (int i = idx0; i < CC * CC; i += stride) Wproj_bf[i] = f2bf(Wproj[i]);
        return;
    }

    const int w = tid >> 6, lane = tid & 63, quad = lane >> 4, l15 = lane & 15;
    const int row0 = blk * 16;
    const int oc = grp * 4 + w;                 // 0..11
    __shared__ float vt[4][16][17];

    const float* xr = x + (size_t)(row0 + l15) * CC + quad * 8;
    short8 a0 = pack8(xr);
    short8 a1 = pack8(xr + 32);

    const float* wr = Wqkv + (size_t)(oc * 16 + l15) * CC + quad * 8;
    short8 b0 = pack8(wr);
    short8 b1 = pack8(wr + 32);
    f32x4 acc = {0.f, 0.f, 0.f, 0.f};
    acc = MFMA16(a0, b0, acc);
    acc = MFMA16(a1, b1, acc);
    const float bias = bqkv[oc * 16 + l15];

    if (oc < 4) {
        const int c = oc * 16 + l15;
        #pragma unroll
        for (int r = 0; r < 4; ++r)
            q_bf[(size_t)(row0 + quad * 4 + r) * CC + c] = f2bf((acc[r] + bias) * 0.125f);
    } else if (oc < 8) {
        const int c = (oc - 4) * 16 + l15;
        #pragma unroll
        for (int r = 0; r < 4; ++r)
            k_bf[(size_t)(row0 + quad * 4 + r) * CC + c] = f2bf(acc[r] + bias);
    } else {
        #pragma unroll
        for (int r = 0; r < 4; ++r) vt[w][quad * 4 + r][l15] = acc[r] + bias;
        const int c_l = lane >> 2;
        const int tbase = (lane & 3) * 4;
        const int b = row0 >> 10, t0v = row0 & (TT - 1);
        u16 p[4];
        #pragma unroll
        for (int tt2 = 0; tt2 < 4; ++tt2) p[tt2] = f2bf(vt[w][tbase + tt2][c_l]);
        unsigned long long pk = (unsigned long long)p[0] | ((unsigned long long)p[1] << 16)
                              | ((unsigned long long)p[2] << 32) | ((unsigned long long)p[3] << 48);
        // vT2[b][sp][c][e0..e0+3]
        const int c = (oc - 8) * 16 + c_l;
        const int sp = (t0v + tbase) >> 3;
        const int e0 = tbase & 7;                 // 0 or 4
        *(unsigned long long*)&vT_bf[(((size_t)(b * 128 + sp) * CC + c) << 3) + e0] = pk;
    }
}

// ---------------------------------------------------------------------------
// K2 (R6): identical math/structure to R5's verified kernel; ONLY the block
// mapping changes. R5 post-mortem: attn is latency-bound on cross-XCD
// re-fetches (FETCH 9.5MB vs 3.4MB unique, 270 GB/s latency signature) —
// x-major grid round-robins adjacent blocks across XCDs, so each XCD's 4MB
// L2 must hold all 8 batches' K/V (~8MB) -> thrash. R6: grid (512), with
//   b = blockIdx.x & 7, tt = 63 - (blockIdx.x >> 3)
// Under the measured dispatch-index%8 -> XCD round-robin (m09/HK), all 64
// blocks of batch b land on XCD b: per-XCD working set ~800KB << 4MB L2.
// 64 blocks = 32 CUs x 2 blocks = exactly one XCD; heavy tiles first ✓.
// Pure scheduling change — no correctness dependence on the mapping.
// ---------------------------------------------------------------------------
#define WBSTRIDE 4160   // per-wave LDS: pt(1280) + a2(2304) = 3584; merge 4096

__global__ __launch_bounds__(512, 2) void attn_loop_kernel(const u16* __restrict__ q_bf,
                                                           const u16* __restrict__ k_bf,
                                                           const u16* __restrict__ vT_bf,
                                                           const u16* __restrict__ embk_pad,
                                                           const u16* __restrict__ embvT_pad,
                                                           const u16* __restrict__ Wproj_bf,
                                                           const float* __restrict__ bproj,
                                                           float* __restrict__ out) {
    const int b = blockIdx.x & 7;                 // XCD-colocate: batch b -> XCD b
    const int tt = 63 - (blockIdx.x >> 3);        // heavy tiles first per XCD
    const int t0 = tt * 16;
    const int nst = (t0 >> 5) + 1;

    const int tid = threadIdx.x;
    const int w = tid >> 6, lane = tid & 63, quad = lane >> 4, l15 = lane & 15;

    __shared__ __align__(16) char wbuf[8][WBSTRIDE];
    __shared__ float lpart[8][16];
    __shared__ float Ls[16];
    __shared__ __align__(16) u16 yA[16 * 64];

    u16* pt = (u16*)(wbuf[w]);                    // 16*40 bf16
    u16* a2 = (u16*)(wbuf[w] + 1280);             // 16*72 bf16 (skewed P)

    f32x4 acc[4];
    #pragma unroll
    for (int nb = 0; nb < 4; ++nb) acc[nb] = (f32x4){0.f, 0.f, 0.f, 0.f};
    float rsum[4] = {0.f, 0.f, 0.f, 0.f};

    // hoisted Q fragments (q pre-scaled by 0.125) — reused across all s-tiles
    const u16* qrow = q_bf + (size_t)((b << 10) + t0 + l15) * CC;
    short8 aq0 = *(const short8*)(qrow + quad * 8);
    short8 aq1 = *(const short8*)(qrow + 32 + quad * 8);

    for (int st = w; st < nst; st += 8) {
        const int s0 = st * 32;
        const int dcol0 = t0 - s0;
        const int dbase = t0 - s0 - 31;

        // ==== issue ALL of this round's global loads up front ====
        const u16* krow0 = k_bf + (size_t)((b << 10) + s0 + l15) * CC;
        const u16* krow1 = k_bf + (size_t)((b << 10) + s0 + 16 + l15) * CC;
        short8 kb00 = *(const short8*)(krow0 + quad * 8);
        short8 kb01 = *(const short8*)(krow0 + 32 + quad * 8);
        short8 kb10 = *(const short8*)(krow1 + quad * 8);
        short8 kb11 = *(const short8*)(krow1 + 32 + quad * 8);

        short8 eb[3][2];
        #pragma unroll
        for (int nb = 0; nb < 3; ++nb) {
            const u16* erow = embk_pad + (size_t)(dbase + 32 + nb * 16 + l15) * CC;
            eb[nb][0] = *(const short8*)(erow + quad * 8);
            eb[nb][1] = *(const short8*)(erow + 32 + quad * 8);
        }

        // vT2[b][s0/8 + quad][c][0..7]: lane-contiguous panels
        short8 bv[4];
        #pragma unroll
        for (int nb = 0; nb < 4; ++nb) {
            const u16* vp = vT_bf + (((size_t)(b * 128 + (s0 >> 3) + quad) * CC + nb * 16 + l15) << 3);
            bv[nb] = *(const short8*)vp;
        }

        // embvT2[(dcol0+kk*32)/8 + quad][c][0..7]
        short8 be[2][4];
        #pragma unroll
        for (int kk = 0; kk < 2; ++kk) {
            const int dp0 = (dcol0 + kk * 32) >> 3;
            #pragma unroll
            for (int nb = 0; nb < 4; ++nb) {
                const u16* ep = embvT_pad + (((size_t)(dp0 + quad) * CC + nb * 16 + l15) << 3);
                be[kk][nb] = *(const short8*)ep;
            }
        }

        // ==== content scores: 16x32 tile ====
        f32x4 sc[2];
        {
            f32x4 a = {0.f, 0.f, 0.f, 0.f};
            a = MFMA16(aq0, kb00, a);
            a = MFMA16(aq1, kb01, a);
            sc[0] = a;
        }
        {
            f32x4 a = {0.f, 0.f, 0.f, 0.f};
            a = MFMA16(aq0, kb10, a);
            a = MFMA16(aq1, kb11, a);
            sc[1] = a;
        }

        // ==== relative band: 3 MFMAs kept in C-layout registers ====
        f32x4 bnd[3];
        #pragma unroll
        for (int nb = 0; nb < 3; ++nb) {
            f32x4 a = {0.f, 0.f, 0.f, 0.f};
            a = MFMA16(aq0, eb[nb][0], a);
            a = MFMA16(aq1, eb[nb][1], a);
            bnd[nb] = a;
        }

        // ==== band via cross-lane shuffles + masked p = exp(score) ====
        u16 pb0[4], pb1[4];
        #pragma unroll
        for (int r = 0; r < 4; ++r) {
            const int i = quad * 4 + r;
            const int u0 = 31 + i - l15;
            const int src = (quad << 4) | (u0 & 15);
            const float v0 = __shfl(bnd[0][r], src, 64);
            const float v1 = __shfl(bnd[1][r], src, 64);
            const float v2 = __shfl(bnd[2][r], src, 64);
            const bool hi = (u0 >= 32);
            {   // cb = 0: j = l15
                const float rb = hi ? v2 : v1;
                const int d = t0 - s0 + i - l15;
                float pv = (d >= 0) ? __expf(sc[0][r] + rb) : 0.f;
                pb0[r] = f2bf(pv);
                rsum[r] += bf2f(pb0[r]);
            }
            {   // cb = 1: j = 16+l15
                const float rb = hi ? v1 : v0;
                const int d = t0 - s0 + i - 16 - l15;
                float pv = (d >= 0) ? __expf(sc[1][r] + rb) : 0.f;
                pb1[r] = f2bf(pv);
                rsum[r] += bf2f(pb1[r]);
            }
        }

        // ==== write P: row-major (pt) and skewed (a2); in-wave DS order ====
        u32x4 z = {0u, 0u, 0u, 0u};
        #pragma unroll
        for (int e = 0; e < 3; ++e) {              // 144 u32x4 = 16*72 u16
            int idx = lane + e * 64;
            if (idx < 144) ((u32x4*)a2)[idx] = z;
        }
        #pragma unroll
        for (int r = 0; r < 4; ++r) {
            const int i = quad * 4 + r;
            pt[i * 40 + l15] = pb0[r];
            pt[i * 40 + 16 + l15] = pb1[r];
            a2[i * 72 + (32 + i - l15)] = pb0[r];
            a2[i * 72 + (16 + i - l15)] = pb1[r];
        }

        // ==== y1 += P @ V ====
        short8 aP = *(const short8*)(pt + l15 * 40 + quad * 8);
        #pragma unroll
        for (int nb = 0; nb < 4; ++nb)
            acc[nb] = MFMA16(aP, bv[nb], acc[nb]);

        // ==== y2 += skew(P) @ embv band ====
        #pragma unroll
        for (int kk = 0; kk < 2; ++kk) {
            short8 a2f = *(const short8*)(a2 + l15 * 72 + kk * 32 + quad * 8);
            #pragma unroll
            for (int nb = 0; nb < 4; ++nb)
                acc[nb] = MFMA16(a2f, be[kk][nb], acc[nb]);
        }
    }

    // ---- per-wave row-sum reduction ----
    #pragma unroll
    for (int msk = 1; msk < 16; msk <<= 1)
        #pragma unroll
        for (int r = 0; r < 4; ++r) rsum[r] += __shfl_xor(rsum[r], msk, 64);
    if (l15 == 0) {
        #pragma unroll
        for (int r = 0; r < 4; ++r) lpart[w][quad * 4 + r] = rsum[r];
    }

    // ---- wave partial Y -> unioned per-wave LDS region ----
    float* ypw = (float*)(wbuf[w]);
    #pragma unroll
    for (int nb = 0; nb < 4; ++nb)
        #pragma unroll
        for (int r = 0; r < 4; ++r)
            ypw[(quad * 4 + r) * 64 + nb * 16 + l15] = acc[nb][r];
    __syncthreads();

    // ---- merge 8 wave partials (threads 0..255 own the 16x64 tile) ----
    const int i = tid >> 4, c0 = (tid * 4) & 63;
    float4 Y = {0.f, 0.f, 0.f, 0.f};
    if (tid < 256) {
        #pragma unroll
        for (int ww = 0; ww < 8; ++ww) {
            const float* src = (const float*)(wbuf[ww]);
            Y.x += src[i * 64 + c0];
            Y.y += src[i * 64 + c0 + 1];
            Y.z += src[i * 64 + c0 + 2];
            Y.w += src[i * 64 + c0 + 3];
        }
        if (tid < 16) {
            float L = 0.f;
            #pragma unroll
            for (int ww = 0; ww < 8; ++ww) L += lpart[ww][tid];
            Ls[tid] = L;
        }
    }
    __syncthreads();

    // ---- normalize + bf16 pack ----
    if (tid < 256) {
        const float inv = 1.0f / Ls[i];
        u16 y4[4] = { f2bf(Y.x * inv), f2bf(Y.y * inv), f2bf(Y.z * inv), f2bf(Y.w * inv) };
        *(unsigned long long*)&yA[i * 64 + c0] =
            (unsigned long long)y4[0] | ((unsigned long long)y4[1] << 16)
          | ((unsigned long long)y4[2] << 32) | ((unsigned long long)y4[3] << 48);
    }
    __syncthreads();

    // ---- proj epilogue: waves 0..3 -> output cols w*16 .. +15 ----
    if (w < 4) {
        short8 a0 = *(const short8*)(yA + l15 * 64 + quad * 8);
        short8 a1 = *(const short8*)(yA + l15 * 64 + 32 + quad * 8);
        const u16* wrow = Wproj_bf + (size_t)(w * 16 + l15) * CC;
        short8 wb0 = *(const short8*)(wrow + quad * 8);
        short8 wb1 = *(const short8*)(wrow + 32 + quad * 8);
        f32x4 o = {0.f, 0.f, 0.f, 0.f};
        o = MFMA16(a0, wb0, o);
        o = MFMA16(a1, wb1, o);
        const float bias = bproj[w * 16 + l15];
        #pragma unroll
        for (int r = 0; r < 4; ++r)
            out[(size_t)((b << 10) + t0 + quad * 4 + r) * CC + w * 16 + l15] = o[r] + bias;
    }
}

// ===========================================================================
// Fallback path (round-1 verified fp32 kernels) — used if ws_size < needed.
// ===========================================================================
__global__ __launch_bounds__(192) void qkv_kernel(const float* __restrict__ x,
                                                  const float* __restrict__ Wqkv,
                                                  const float* __restrict__ bqkv,
                                                  float* __restrict__ qkv) {
    __shared__ __align__(16) float xs[CC];
    const int row = blockIdx.x;
    const int j = threadIdx.x;
    if (j < CC) xs[j] = x[row * CC + j];
    __syncthreads();
    const float* w = Wqkv + j * CC;
    float acc = bqkv[j];
    #pragma unroll
    for (int c = 0; c < CC; c += 4) {
        float4 wq = *(const float4*)(w + c);
        float4 xq = *(const float4*)(xs + c);
        acc += wq.x * xq.x + wq.y * xq.y + wq.z * xq.z + wq.w * xq.w;
    }
    qkv[row * 192 + j] = acc;
}

__global__ __launch_bounds__(256) void attn_kernel(const float* __restrict__ qkv,
                                                   const float* __restrict__ embk,
                                                   const float* __restrict__ embv,
                                                   const float* __restrict__ Wproj,
                                                   const float* __restrict__ bproj,
                                                   float* __restrict__ out) {
    __shared__ __align__(16) float qs[CC];
    __shared__ __align__(16) float sc[TT];
    __shared__ float red[256];
    __shared__ float yred[4][CC];
    const int bt = blockIdx.x;
    const int b = bt >> 10, t = bt & (TT - 1);
    const int tid = threadIdx.x;
    if (tid < CC) qs[tid] = qkv[bt * 192 + tid];
    __syncthreads();
    float lmax = -1e30f;
    for (int s = tid; s <= t; s += 256) {
        const float* krow = qkv + (b * TT + s) * 192 + 64;
        const float* erow = embk + (t - s) * CC;
        float acc = 0.f;
        #pragma unroll
        for (int c = 0; c < CC; c += 4) {
            float4 kq = *(const float4*)(krow + c);
            float4 eq = *(const float4*)(erow + c);
            float4 qq = *(const float4*)(qs + c);
            acc += qq.x * (kq.x + eq.x) + qq.y * (kq.y + eq.y)
                 + qq.z * (kq.z + eq.z) + qq.w * (kq.w + eq.w);
        }
        acc *= 0.125f;
        sc[s] = acc;
        lmax = fmaxf(lmax, acc);
    }
    red[tid] = lmax; __syncthreads();
    for (int off = 128; off > 0; off >>= 1) { if (tid < off) red[tid] = fmaxf(red[tid], red[tid + off]); __syncthreads(); }
    const float m = red[0]; __syncthreads();
    float lsum = 0.f;
    for (int s = tid; s <= t; s += 256) { float e = __expf(sc[s] - m); sc[s] = e; lsum += e; }
    red[tid] = lsum; __syncthreads();
    for (int off = 128; off > 0; off >>= 1) { if (tid < off) red[tid] += red[tid + off]; __syncthreads(); }
    const float inv = 1.0f / red[0]; __syncthreads();
    const int c = tid & 63, g = tid >> 6;
    float acc = 0.f;
    for (int s = g; s <= t; s += 4) {
        float p = sc[s];
        float vv = qkv[(b * TT + s) * 192 + 128 + c];
        float ev = embv[(t - s) * CC + c];
        acc += p * (vv + ev);
    }
    yred[g][c] = acc * inv;
    __syncthreads();
    if (tid < CC) qs[tid] = yred[0][tid] + yred[1][tid] + yred[2][tid] + yred[3][tid];
    __syncthreads();
    if (tid < CC) {
        const float* w = Wproj + tid * CC;
        float o = bproj[tid];
        #pragma unroll
        for (int cc2 = 0; cc2 < CC; cc2 += 4) {
            float4 wq = *(const float4*)(w + cc2);
            float4 yq = *(const float4*)(qs + cc2);
            o += wq.x * yq.x + wq.y * yq.y + wq.z * yq.z + wq.w * yq.w;
        }
        out[bt * CC + tid] = o;
    }
}

extern "C" void kernel_launch(void* const* d_in, const int* in_sizes, int n_in,
                              void* d_out, int out_size, void* d_ws, size_t ws_size,
                              hipStream_t stream) {
    const float* x     = (const float*)d_in[0];
    const float* Wqkv  = (const float*)d_in[1];
    const float* bqkv  = (const float*)d_in[2];
    const float* embk  = (const float*)d_in[3];
    const float* embv  = (const float*)d_in[4];
    const float* Wproj = (const float*)d_in[5];
    const float* bproj = (const float*)d_in[6];
    float* out = (float*)d_out;

    if (ws_size < WS_NEED) {
        float* qkv = (float*)d_ws;
        qkv_kernel<<<BB * TT, 192, 0, stream>>>(x, Wqkv, bqkv, qkv);
        attn_kernel<<<BB * TT, 256, 0, stream>>>(qkv, embk, embv, Wproj, bproj, out);
        return;
    }

    char* ws = (char*)d_ws;
    u16* q_bf       = (u16*)(ws + OFF_QBF);
    u16* k_bf       = (u16*)(ws + OFF_KBF);
    u16* vT_bf      = (u16*)(ws + OFF_VT);
    u16* embk_pad   = (u16*)(ws + OFF_EKP);
    u16* embvT_pad  = (u16*)(ws + OFF_EVT);
    u16* Wproj_bf   = (u16*)(ws + OFF_WPROJ);

    qkv_prep_kernel<<<dim3(576, 3), 256, 0, stream>>>(x, Wqkv, bqkv, embk, embv, Wproj,
                                                      q_bf, k_bf, vT_bf, embk_pad, embvT_pad, Wproj_bf);
    attn_loop_kernel<<<dim3(512), 512, 0, stream>>>(q_bf, k_bf, vT_bf, embk_pad, embvT_pad,
                                                    Wproj_bf, bproj, out);
}